// Round 1
// baseline (1920.697 us; speedup 1.0000x reference)
//
#include <hip/hip_runtime.h>
#include <cmath>

#define TOKENS 4096
#define DMODEL 1024
#define NHEADS 16
#define HDIM 64

// ---------------------------------------------------------------------------
// GEMM: C[M,N] = A[M,K] @ W[N,K]^T (+ optional bias)   (torch Linear layout)
// BM=BN=128, BK=16, 256 threads, 8x8 microtile, fp32.
// ---------------------------------------------------------------------------
template<int BIAS>
__global__ __launch_bounds__(256)
void gemm_xwT(const float* __restrict__ A, const float* __restrict__ W,
              const float* __restrict__ bias, float* __restrict__ C,
              int M, int N, int K)
{
    __shared__ float As[16][128];
    __shared__ float Bs[16][128];

    const int tid = threadIdx.x;
    const int tx  = tid & 15;       // micro col group
    const int ty  = tid >> 4;       // micro row group
    const int bm  = blockIdx.y;
    const int bn  = blockIdx.x;

    const float* Ablk = A + (size_t)bm * 128 * K;
    const float* Wblk = W + (size_t)bn * 128 * K;

    const int lrow = tid >> 1;        // 0..127
    const int lk   = (tid & 1) * 8;   // 0 or 8

    float acc[8][8];
#pragma unroll
    for (int i = 0; i < 8; ++i)
#pragma unroll
        for (int j = 0; j < 8; ++j) acc[i][j] = 0.f;

    for (int k0 = 0; k0 < K; k0 += 16) {
        // global loads for this tile (issued before the barrier for latency)
        float4 a0 = *(const float4*)(Ablk + (size_t)lrow * K + k0 + lk);
        float4 a1 = *(const float4*)(Ablk + (size_t)lrow * K + k0 + lk + 4);
        float4 b0 = *(const float4*)(Wblk + (size_t)lrow * K + k0 + lk);
        float4 b1 = *(const float4*)(Wblk + (size_t)lrow * K + k0 + lk + 4);

        __syncthreads();   // previous tile fully consumed
        As[lk + 0][lrow] = a0.x; As[lk + 1][lrow] = a0.y;
        As[lk + 2][lrow] = a0.z; As[lk + 3][lrow] = a0.w;
        As[lk + 4][lrow] = a1.x; As[lk + 5][lrow] = a1.y;
        As[lk + 6][lrow] = a1.z; As[lk + 7][lrow] = a1.w;
        Bs[lk + 0][lrow] = b0.x; Bs[lk + 1][lrow] = b0.y;
        Bs[lk + 2][lrow] = b0.z; Bs[lk + 3][lrow] = b0.w;
        Bs[lk + 4][lrow] = b1.x; Bs[lk + 5][lrow] = b1.y;
        Bs[lk + 6][lrow] = b1.z; Bs[lk + 7][lrow] = b1.w;
        __syncthreads();

        for (int kk = 0; kk < 16; ++kk) {
            float av[8], bv[8];
            *(float4*)&av[0] = *(const float4*)&As[kk][ty * 8];
            *(float4*)&av[4] = *(const float4*)&As[kk][ty * 8 + 4];
            *(float4*)&bv[0] = *(const float4*)&Bs[kk][tx * 8];
            *(float4*)&bv[4] = *(const float4*)&Bs[kk][tx * 8 + 4];
#pragma unroll
            for (int i = 0; i < 8; ++i)
#pragma unroll
                for (int j = 0; j < 8; ++j)
                    acc[i][j] = fmaf(av[i], bv[j], acc[i][j]);
        }
    }

    const int row0 = bm * 128 + ty * 8;
    const int col0 = bn * 128 + tx * 8;
#pragma unroll
    for (int i = 0; i < 8; ++i) {
        float outv[8];
#pragma unroll
        for (int j = 0; j < 8; ++j) {
            float v = acc[i][j];
            if constexpr (BIAS) v += bias[col0 + j];
            outv[j] = v;
        }
        float* cp = C + (size_t)(row0 + i) * N + col0;
        *(float4*)(cp + 0) = *(float4*)&outv[0];
        *(float4*)(cp + 4) = *(float4*)&outv[4];
    }
}

// ---------------------------------------------------------------------------
// Flash-style causal attention, fp32.
// Grid: (qblock 0..63, head 0..15). Block: 256 threads.
// Each block: 64 q-rows of one head. K/V staged 64x64 in LDS; online softmax.
// ---------------------------------------------------------------------------
__global__ __launch_bounds__(256)
void flash_attn(const float* __restrict__ Qg, const float* __restrict__ Kg,
                const float* __restrict__ Vg, float* __restrict__ CTX)
{
    __shared__ float Qs[64][68];
    __shared__ float Ks[64][68];
    __shared__ float Vs[64][68];
    __shared__ float Ps[64][68];
    __shared__ float m_s[64], l_s[64], corr_s[64];

    const int tid = threadIdx.x;
    const int tx  = tid & 15;
    const int ty  = tid >> 4;
    const int h   = blockIdx.y;
    const int qb  = blockIdx.x;
    const int r0  = ty * 4;
    const int c0  = tx * 4;

    // load Q tile: rows qb*64.., cols h*64..h*64+63
    {
        const int r  = tid >> 2;
        const int d0 = (tid & 3) * 16;
        const float* src = Qg + (size_t)(qb * 64 + r) * DMODEL + h * HDIM + d0;
        float4 v0 = *(const float4*)(src + 0);
        float4 v1 = *(const float4*)(src + 4);
        float4 v2 = *(const float4*)(src + 8);
        float4 v3 = *(const float4*)(src + 12);
        *(float4*)&Qs[r][d0 + 0]  = v0;
        *(float4*)&Qs[r][d0 + 4]  = v1;
        *(float4*)&Qs[r][d0 + 8]  = v2;
        *(float4*)&Qs[r][d0 + 12] = v3;
    }
    if (tid < 64) { m_s[tid] = -INFINITY; l_s[tid] = 0.f; }

    float o[4][4];
#pragma unroll
    for (int i = 0; i < 4; ++i)
#pragma unroll
        for (int j = 0; j < 4; ++j) o[i][j] = 0.f;

    for (int kb = 0; kb <= qb; ++kb) {
        __syncthreads();   // previous iteration done with Ks/Vs/Ps
        {
            const int r  = tid >> 2;
            const int d0 = (tid & 3) * 16;
            const float* ks = Kg + (size_t)(kb * 64 + r) * DMODEL + h * HDIM + d0;
            const float* vs = Vg + (size_t)(kb * 64 + r) * DMODEL + h * HDIM + d0;
            float4 k0v = *(const float4*)(ks + 0);
            float4 k1v = *(const float4*)(ks + 4);
            float4 k2v = *(const float4*)(ks + 8);
            float4 k3v = *(const float4*)(ks + 12);
            float4 v0v = *(const float4*)(vs + 0);
            float4 v1v = *(const float4*)(vs + 4);
            float4 v2v = *(const float4*)(vs + 8);
            float4 v3v = *(const float4*)(vs + 12);
            *(float4*)&Ks[r][d0 + 0]  = k0v;
            *(float4*)&Ks[r][d0 + 4]  = k1v;
            *(float4*)&Ks[r][d0 + 8]  = k2v;
            *(float4*)&Ks[r][d0 + 12] = k3v;
            *(float4*)&Vs[r][d0 + 0]  = v0v;
            *(float4*)&Vs[r][d0 + 4]  = v1v;
            *(float4*)&Vs[r][d0 + 8]  = v2v;
            *(float4*)&Vs[r][d0 + 12] = v3v;
        }
        __syncthreads();

        // S = (Q K^T) * 0.125 with causal mask
        float s[4][4];
#pragma unroll
        for (int i = 0; i < 4; ++i)
#pragma unroll
            for (int j = 0; j < 4; ++j) s[i][j] = 0.f;

        for (int d4 = 0; d4 < 16; ++d4) {
            float q_[4][4], k_[4][4];
#pragma unroll
            for (int i = 0; i < 4; ++i) {
                float4 t = *(const float4*)&Qs[r0 + i][d4 * 4];
                q_[i][0] = t.x; q_[i][1] = t.y; q_[i][2] = t.z; q_[i][3] = t.w;
            }
#pragma unroll
            for (int j = 0; j < 4; ++j) {
                float4 t = *(const float4*)&Ks[c0 + j][d4 * 4];
                k_[j][0] = t.x; k_[j][1] = t.y; k_[j][2] = t.z; k_[j][3] = t.w;
            }
#pragma unroll
            for (int i = 0; i < 4; ++i)
#pragma unroll
                for (int j = 0; j < 4; ++j)
#pragma unroll
                    for (int d = 0; d < 4; ++d)
                        s[i][j] = fmaf(q_[i][d], k_[j][d], s[i][j]);
        }

        const bool diag = (kb == qb);
#pragma unroll
        for (int i = 0; i < 4; ++i) {
            float rowv[4];
#pragma unroll
            for (int j = 0; j < 4; ++j) {
                float v = s[i][j] * 0.125f;
                if (diag && (c0 + j > r0 + i)) v = -INFINITY;
                rowv[j] = v;
            }
            *(float4*)&Ps[r0 + i][c0] = *(float4*)&rowv[0];
        }
        __syncthreads();

        // online softmax row pass (one wave: 64 rows)
        if (tid < 64) {
            const int r = tid;
            float mprev = m_s[r];
            float mx = mprev;
            for (int c4 = 0; c4 < 16; ++c4) {
                float4 p = *(const float4*)&Ps[r][c4 * 4];
                mx = fmaxf(mx, fmaxf(fmaxf(p.x, p.y), fmaxf(p.z, p.w)));
            }
            float corr = __expf(mprev - mx);
            float sum = 0.f;
            for (int c4 = 0; c4 < 16; ++c4) {
                float4 p = *(const float4*)&Ps[r][c4 * 4];
                p.x = __expf(p.x - mx); p.y = __expf(p.y - mx);
                p.z = __expf(p.z - mx); p.w = __expf(p.w - mx);
                *(float4*)&Ps[r][c4 * 4] = p;
                sum += (p.x + p.y) + (p.z + p.w);
            }
            m_s[r] = mx;
            l_s[r] = l_s[r] * corr + sum;
            corr_s[r] = corr;
        }
        __syncthreads();

        // O = O*corr + P @ V
        float cr[4];
#pragma unroll
        for (int i = 0; i < 4; ++i) cr[i] = corr_s[r0 + i];
#pragma unroll
        for (int i = 0; i < 4; ++i)
#pragma unroll
            for (int j = 0; j < 4; ++j) o[i][j] *= cr[i];

        for (int k4 = 0; k4 < 16; ++k4) {
            float p_[4][4], v_[4][4];
#pragma unroll
            for (int i = 0; i < 4; ++i) {
                float4 t = *(const float4*)&Ps[r0 + i][k4 * 4];
                p_[i][0] = t.x; p_[i][1] = t.y; p_[i][2] = t.z; p_[i][3] = t.w;
            }
#pragma unroll
            for (int kk = 0; kk < 4; ++kk) {
                float4 t = *(const float4*)&Vs[k4 * 4 + kk][c0];
                v_[kk][0] = t.x; v_[kk][1] = t.y; v_[kk][2] = t.z; v_[kk][3] = t.w;
            }
#pragma unroll
            for (int i = 0; i < 4; ++i)
#pragma unroll
                for (int j = 0; j < 4; ++j)
#pragma unroll
                    for (int kk = 0; kk < 4; ++kk)
                        o[i][j] = fmaf(p_[i][kk], v_[kk][j], o[i][j]);
        }
    }

    // normalize and store ctx
    float inv[4];
#pragma unroll
    for (int i = 0; i < 4; ++i) inv[i] = 1.f / l_s[r0 + i];
#pragma unroll
    for (int i = 0; i < 4; ++i) {
        float outv[4];
#pragma unroll
        for (int j = 0; j < 4; ++j) outv[j] = o[i][j] * inv[i];
        *(float4*)(CTX + (size_t)(qb * 64 + r0 + i) * DMODEL + h * HDIM + c0) =
            *(float4*)&outv[0];
    }
}

// ---------------------------------------------------------------------------
extern "C" void kernel_launch(void* const* d_in, const int* in_sizes, int n_in,
                              void* d_out, int out_size, void* d_ws, size_t ws_size,
                              hipStream_t stream)
{
    const float* x  = (const float*)d_in[0];
    const float* Wq = (const float*)d_in[1];
    const float* Wk = (const float*)d_in[2];
    const float* Wv = (const float*)d_in[3];
    const float* Wo = (const float*)d_in[4];
    const float* bo = (const float*)d_in[5];
    float* out = (float*)d_out;

    float* Q   = (float*)d_ws;
    float* K   = Q + (size_t)TOKENS * DMODEL;
    float* V   = K + (size_t)TOKENS * DMODEL;
    float* CTX = V + (size_t)TOKENS * DMODEL;

    dim3 gGemm(DMODEL / 128, TOKENS / 128);   // (8, 32)
    dim3 blk(256);

    gemm_xwT<0><<<gGemm, blk, 0, stream>>>(x, Wq, nullptr, Q, TOKENS, DMODEL, DMODEL);
    gemm_xwT<0><<<gGemm, blk, 0, stream>>>(x, Wk, nullptr, K, TOKENS, DMODEL, DMODEL);
    gemm_xwT<0><<<gGemm, blk, 0, stream>>>(x, Wv, nullptr, V, TOKENS, DMODEL, DMODEL);

    dim3 gAttn(TOKENS / 64, NHEADS);          // (64, 16)
    flash_attn<<<gAttn, blk, 0, stream>>>(Q, K, V, CTX);

    gemm_xwT<1><<<gGemm, blk, 0, stream>>>(CTX, Wo, bo, out, TOKENS, DMODEL, DMODEL);
}

// Round 5
// 354.013 us; speedup vs baseline: 5.4255x; 5.4255x over previous
//
#include <hip/hip_runtime.h>
#include <cmath>

#define TOKENS 4096
#define DMODEL 1024
#define NHEADS 16
#define HDIM 64

typedef _Float16 f16;
typedef _Float16 half8 __attribute__((ext_vector_type(8)));
typedef float f32x4 __attribute__((ext_vector_type(4)));

// ---------------------------------------------------------------------------
// Swizzled LDS tiles: rows of 128 bytes = 8 chunks of 16 B.
// Logical chunk g of row r lives at physical chunk g ^ (r & 7)  (T2-style).
// Staged via global_load_lds with PRE-SWIZZLED per-lane global source
// (linear LDS dest, m173/m201 pattern).
// ---------------------------------------------------------------------------
__device__ __forceinline__ void* lds_chunk(void* base, int row, int chunk) {
    int p = chunk ^ (row & 7);
    return (char*)base + row * 128 + p * 16;
}

__device__ __forceinline__ void gload16(const void* g, void* lds) {
    __builtin_amdgcn_global_load_lds(
        (const __attribute__((address_space(1))) unsigned int*)g,
        (__attribute__((address_space(3))) unsigned int*)lds, 16, 0, 0);
}

// ---------------------------------------------------------------------------
__global__ __launch_bounds__(256)
void cvt_f32_f16(const float* __restrict__ in, f16* __restrict__ out, int n8)
{
    int i = blockIdx.x * 256 + threadIdx.x;
    if (i >= n8) return;
    float4 a = ((const float4*)in)[i * 2];
    float4 b = ((const float4*)in)[i * 2 + 1];
    half8 h;
    h[0] = (f16)a.x; h[1] = (f16)a.y; h[2] = (f16)a.z; h[3] = (f16)a.w;
    h[4] = (f16)b.x; h[5] = (f16)b.y; h[6] = (f16)b.z; h[7] = (f16)b.w;
    ((half8*)out)[i] = h;
}

// ---------------------------------------------------------------------------
// V [4096][1024] f16 -> Vt [1024][4096] f16   (64x64 LDS tiles)
// ---------------------------------------------------------------------------
__global__ __launch_bounds__(256)
void transpose_v(const f16* __restrict__ V, f16* __restrict__ Vt)
{
    __shared__ f16 T[64][66];
    const int tid = threadIdx.x;
    const int t0 = blockIdx.x * 64, d0 = blockIdx.y * 64;
    const int r = tid >> 3, c = (tid & 7) * 8;
#pragma unroll
    for (int it = 0; it < 2; ++it) {
        int row = r + it * 32;
        half8 v = *(const half8*)(V + (size_t)(t0 + row) * DMODEL + d0 + c);
#pragma unroll
        for (int j = 0; j < 8; ++j) T[row][c + j] = v[j];
    }
    __syncthreads();
#pragma unroll
    for (int it = 0; it < 2; ++it) {
        int drow = r + it * 32;
        half8 v;
#pragma unroll
        for (int j = 0; j < 8; ++j) v[j] = T[c + j][drow];
        *(half8*)(Vt + (size_t)(d0 + drow) * TOKENS + t0 + c) = v;
    }
}

// ---------------------------------------------------------------------------
// f16 MFMA GEMM: C[M,N] = A[M,K] @ W[N,K]^T
// 128x128 tile, BK=64, 256 thr (4 waves), each wave 64x64 = 4x4 frags.
// MODE 0: fused QKV (N=3072, select Wq/Wk/Wv by bn>>3), f16 out.
// MODE 1: f32 out + bias (final projection).
// ---------------------------------------------------------------------------
template<int MODE>
__global__ __launch_bounds__(256)
void gemm_f16(const f16* __restrict__ A, const f16* __restrict__ W0,
              const f16* __restrict__ W1, const f16* __restrict__ W2,
              const float* __restrict__ bias,
              f16* __restrict__ O0, f16* __restrict__ O1, f16* __restrict__ O2,
              float* __restrict__ Of, int K)
{
    __shared__ __align__(16) f16 As[128 * 64];
    __shared__ __align__(16) f16 Bs[128 * 64];
    const int tid = threadIdx.x, lane = tid & 63, wv = tid >> 6;
    const int g = lane >> 4, ln15 = lane & 15;
    const int bm = blockIdx.y, bn = blockIdx.x;
    const int rowInCall = lane >> 3, p = lane & 7;

    const f16* W = W0;
    f16* Oq = O0;
    int ncol0 = bn * 128;
    if (MODE == 0) {
        int which = bn >> 3;
        W  = which == 0 ? W0 : (which == 1 ? W1 : W2);
        Oq = which == 0 ? O0 : (which == 1 ? O1 : O2);
        ncol0 = (bn & 7) * 128;
    }

    f32x4 acc[4][4] = {};
    const size_t rowB = (size_t)K * 2;   // row stride in bytes
    const int wm = (wv >> 1) * 64, wn = (wv & 1) * 64;

    for (int kt = 0; kt < K / 64; ++kt) {
        if (kt) __syncthreads();
        // stage A and B tiles: wave wv issues calls 4wv..4wv+3 of each
        for (int c = wv * 4; c < wv * 4 + 4; ++c) {
            int r = c * 8 + rowInCall;
            int gc = p ^ (r & 7);                       // pre-swizzled source chunk
            const char* ga = (const char*)A + (size_t)(bm * 128 + r) * rowB + kt * 128 + gc * 16;
            gload16(ga, (char*)As + c * 1024);
            const char* gb = (const char*)W + (size_t)(ncol0 + r) * rowB + kt * 128 + gc * 16;
            gload16(gb, (char*)Bs + c * 1024);
        }
        __syncthreads();

#pragma unroll
        for (int ks = 0; ks < 2; ++ks) {
            half8 a[4], b[4];
#pragma unroll
            for (int mf = 0; mf < 4; ++mf)
                a[mf] = *(const half8*)lds_chunk(As, wm + mf * 16 + ln15, ks * 4 + g);
#pragma unroll
            for (int nf = 0; nf < 4; ++nf)
                b[nf] = *(const half8*)lds_chunk(Bs, wn + nf * 16 + ln15, ks * 4 + g);
#pragma unroll
            for (int mf = 0; mf < 4; ++mf)
#pragma unroll
                for (int nf = 0; nf < 4; ++nf)
                    acc[mf][nf] = __builtin_amdgcn_mfma_f32_16x16x32_f16(
                        a[mf], b[nf], acc[mf][nf], 0, 0, 0);
        }
    }

#pragma unroll
    for (int mf = 0; mf < 4; ++mf)
#pragma unroll
        for (int nf = 0; nf < 4; ++nf)
#pragma unroll
            for (int r = 0; r < 4; ++r) {
                int row = bm * 128 + wm + mf * 16 + g * 4 + r;
                int col = wn + nf * 16 + ln15;
                if (MODE == 0) {
                    Oq[(size_t)row * 1024 + ncol0 + col] = (f16)acc[mf][nf][r];
                } else {
                    int gc2 = bn * 128 + col;
                    Of[(size_t)row * 1024 + gc2] = acc[mf][nf][r] + bias[gc2];
                }
            }
}

// ---------------------------------------------------------------------------
// Flash attention, f16 MFMA. Block = (head, 64 q-rows); 4 waves x 16 q-rows.
// K tile [64t][64d], Vt tile [64d][64t] staged swizzled; P per-wave in LDS.
// Softmax fully wave-parallel in C-fragment layout (shfl_xor over 16-group).
// ---------------------------------------------------------------------------
__global__ __launch_bounds__(256)
void attn_f16(const f16* __restrict__ Qf, const f16* __restrict__ Kf,
              const f16* __restrict__ Vt, f16* __restrict__ Ctx)
{
    __shared__ __align__(16) f16 Ks[64 * 64];
    __shared__ __align__(16) f16 Vs[64 * 64];
    __shared__ __align__(16) f16 Ps[4][16 * 64];
    const int tid = threadIdx.x, lane = tid & 63, wv = tid >> 6;
    const int g = lane >> 4, ln15 = lane & 15;
    const int qb = blockIdx.x, h = blockIdx.y;
    const int rowInCall = lane >> 3, p = lane & 7;

    // Q fragments live in registers for the whole kernel
    const int qrow = qb * 64 + wv * 16 + ln15;
    half8 qfr[2];
#pragma unroll
    for (int ks = 0; ks < 2; ++ks)
        qfr[ks] = *(const half8*)(Qf + (size_t)qrow * DMODEL + h * HDIM + ks * 32 + g * 8);

    f32x4 O[4] = {};
    float m_r[4] = {-1e30f, -1e30f, -1e30f, -1e30f};
    float l_r[4] = {0.f, 0.f, 0.f, 0.f};
    const int qrow_g = qb * 64 + wv * 16 + g * 4;   // + r
    char* Pb = (char*)Ps[wv];

    for (int kb = 0; kb <= qb; ++kb) {
        if (kb) __syncthreads();
        // stage K and Vt tiles (8 calls each, 2 per wave)
        for (int c = wv * 2; c < wv * 2 + 2; ++c) {
            int r = c * 8 + rowInCall;
            int gc = p ^ (r & 7);
            const char* gk = (const char*)Kf + (size_t)(kb * 64 + r) * (DMODEL * 2)
                             + h * 128 + gc * 16;
            gload16(gk, (char*)Ks + c * 1024);
            const char* gv = (const char*)Vt + (size_t)(h * 64 + r) * (TOKENS * 2)
                             + kb * 128 + gc * 16;
            gload16(gv, (char*)Vs + c * 1024);
        }
        __syncthreads();

        // S = Q K^T  (per wave: 16 q x 64 t)
        f32x4 s[4] = {};
#pragma unroll
        for (int ks = 0; ks < 2; ++ks)
#pragma unroll
            for (int tf = 0; tf < 4; ++tf) {
                half8 b = *(const half8*)lds_chunk(Ks, tf * 16 + ln15, ks * 4 + g);
                s[tf] = __builtin_amdgcn_mfma_f32_16x16x32_f16(qfr[ks], b, s[tf], 0, 0, 0);
            }

        // scale + causal mask + per-row tile max
        const bool diag = (kb == qb);
        float tmax[4] = {-1e30f, -1e30f, -1e30f, -1e30f};
#pragma unroll
        for (int tf = 0; tf < 4; ++tf) {
            int t = kb * 64 + tf * 16 + ln15;
#pragma unroll
            for (int r = 0; r < 4; ++r) {
                float v = s[tf][r] * 0.125f;
                if (diag && t > qrow_g + r) v = -1e30f;
                s[tf][r] = v;
                tmax[r] = fmaxf(tmax[r], v);
            }
        }
#pragma unroll
        for (int r = 0; r < 4; ++r)
#pragma unroll
            for (int mm = 1; mm < 16; mm <<= 1)
                tmax[r] = fmaxf(tmax[r], __shfl_xor(tmax[r], mm, 64));

        float corr[4];
#pragma unroll
        for (int r = 0; r < 4; ++r) {
            float mnew = fmaxf(m_r[r], tmax[r]);
            corr[r] = __expf(m_r[r] - mnew);
            m_r[r] = mnew;
        }

        // P = exp(S - m), row sums, write P (swizzled, wave-private)
        float tsum[4] = {0.f, 0.f, 0.f, 0.f};
#pragma unroll
        for (int tf = 0; tf < 4; ++tf)
#pragma unroll
            for (int r = 0; r < 4; ++r) {
                float e = __expf(s[tf][r] - m_r[r]);
                tsum[r] += e;
                int row = g * 4 + r;
                int t = tf * 16 + ln15;
                int pc = (t >> 3) ^ (row & 7);
                *(f16*)(Pb + row * 128 + pc * 16 + (t & 7) * 2) = (f16)e;
            }
#pragma unroll
        for (int r = 0; r < 4; ++r) {
#pragma unroll
            for (int mm = 1; mm < 16; mm <<= 1)
                tsum[r] += __shfl_xor(tsum[r], mm, 64);
            l_r[r] = l_r[r] * corr[r] + tsum[r];
        }

        // rescale O, then O += P @ V
#pragma unroll
        for (int df = 0; df < 4; ++df)
#pragma unroll
            for (int r = 0; r < 4; ++r)
                O[df][r] *= corr[r];

        // P ds_writes -> P ds_reads (same wave). Rule #18: the inline-asm
        // waitcnt needs a sched_barrier after it so hipcc can't reorder.
        asm volatile("s_waitcnt lgkmcnt(0)" ::: "memory");
        __builtin_amdgcn_sched_barrier(0);
#pragma unroll
        for (int ks = 0; ks < 2; ++ks) {
            half8 pa = *(const half8*)lds_chunk(Pb, ln15, ks * 4 + g);
#pragma unroll
            for (int df = 0; df < 4; ++df) {
                half8 b = *(const half8*)lds_chunk(Vs, df * 16 + ln15, ks * 4 + g);
                O[df] = __builtin_amdgcn_mfma_f32_16x16x32_f16(pa, b, O[df], 0, 0, 0);
            }
        }
    }

#pragma unroll
    for (int df = 0; df < 4; ++df)
#pragma unroll
        for (int r = 0; r < 4; ++r) {
            int row = qrow_g + r;
            int col = h * HDIM + df * 16 + ln15;
            Ctx[(size_t)row * DMODEL + col] = (f16)(O[df][r] / l_r[r]);
        }
}

// ---------------------------------------------------------------------------
extern "C" void kernel_launch(void* const* d_in, const int* in_sizes, int n_in,
                              void* d_out, int out_size, void* d_ws, size_t ws_size,
                              hipStream_t stream)
{
    const float* x  = (const float*)d_in[0];
    const float* Wq = (const float*)d_in[1];
    const float* Wk = (const float*)d_in[2];
    const float* Wv = (const float*)d_in[3];
    const float* Wo = (const float*)d_in[4];
    const float* bo = (const float*)d_in[5];
    float* out = (float*)d_out;

    const size_t XN = (size_t)TOKENS * DMODEL;   // 4M
    const size_t WN = (size_t)DMODEL * DMODEL;   // 1M
    f16* xh  = (f16*)d_ws;
    f16* Wqh = xh  + XN;
    f16* Wkh = Wqh + WN;
    f16* Wvh = Wkh + WN;
    f16* Woh = Wvh + WN;
    f16* Q   = Woh + WN;
    f16* Kb  = Q   + XN;
    f16* Vb  = Kb  + XN;
    f16* Vtb = Vb  + XN;
    f16* Ctx = Vtb + XN;                          // total 28M f16 = 56 MB

    cvt_f32_f16<<<2048, 256, 0, stream>>>(x,  xh,  (int)(XN / 8));
    cvt_f32_f16<<<512,  256, 0, stream>>>(Wq, Wqh, (int)(WN / 8));
    cvt_f32_f16<<<512,  256, 0, stream>>>(Wk, Wkh, (int)(WN / 8));
    cvt_f32_f16<<<512,  256, 0, stream>>>(Wv, Wvh, (int)(WN / 8));
    cvt_f32_f16<<<512,  256, 0, stream>>>(Wo, Woh, (int)(WN / 8));

    gemm_f16<0><<<dim3(24, 32), 256, 0, stream>>>(xh, Wqh, Wkh, Wvh, nullptr,
                                                  Q, Kb, Vb, nullptr, DMODEL);
    transpose_v<<<dim3(TOKENS / 64, DMODEL / 64), 256, 0, stream>>>(Vb, Vtb);
    attn_f16<<<dim3(TOKENS / 64, NHEADS), 256, 0, stream>>>(Q, Kb, Vtb, Ctx);
    gemm_f16<1><<<dim3(8, 32), 256, 0, stream>>>(Ctx, Woh, nullptr, nullptr, bo,
                                                 nullptr, nullptr, nullptr, out, DMODEL);
}

// Round 6
// 246.752 us; speedup vs baseline: 7.7839x; 1.4347x over previous
//
#include <hip/hip_runtime.h>
#include <cmath>

#define TOKENS 4096
#define DMODEL 1024
#define NHEADS 16
#define HDIM 64

typedef _Float16 f16;
typedef _Float16 half8 __attribute__((ext_vector_type(8)));
typedef float f32x4 __attribute__((ext_vector_type(4)));

// ---------------------------------------------------------------------------
// Swizzled LDS tiles: rows of 128 bytes = 8 chunks of 16 B.
// Logical chunk g of row r lives at physical chunk g ^ (r & 7).
// Staged via global_load_lds with PRE-SWIZZLED per-lane global source.
// ---------------------------------------------------------------------------
__device__ __forceinline__ void* lds_chunk(void* base, int row, int chunk) {
    int p = chunk ^ (row & 7);
    return (char*)base + row * 128 + p * 16;
}

__device__ __forceinline__ void gload16(const void* g, void* lds) {
    __builtin_amdgcn_global_load_lds(
        (const __attribute__((address_space(1))) unsigned int*)g,
        (__attribute__((address_space(3))) unsigned int*)lds, 16, 0, 0);
}

// ---------------------------------------------------------------------------
// Fused f32->f16 convert for x, Wq, Wk, Wv, Wo (one launch instead of five).
// n8 units of 8 elements. Segment boundaries are multiples of 512 blocks ->
// branches are block-uniform.
// ---------------------------------------------------------------------------
__global__ __launch_bounds__(256)
void cvt_all(const float* __restrict__ x,  const float* __restrict__ Wq,
             const float* __restrict__ Wk, const float* __restrict__ Wv,
             const float* __restrict__ Wo,
             f16* xh, f16* Wqh, f16* Wkh, f16* Wvh, f16* Woh)
{
    int i = blockIdx.x * 256 + threadIdx.x;
    const float* src; f16* dst; int off;
    if      (i < 524288) { src = x;  dst = xh;  off = i; }
    else if (i < 655360) { src = Wq; dst = Wqh; off = i - 524288; }
    else if (i < 786432) { src = Wk; dst = Wkh; off = i - 655360; }
    else if (i < 917504) { src = Wv; dst = Wvh; off = i - 786432; }
    else                 { src = Wo; dst = Woh; off = i - 917504; }
    float4 a = ((const float4*)src)[off * 2];
    float4 b = ((const float4*)src)[off * 2 + 1];
    half8 hv;
    hv[0] = (f16)a.x; hv[1] = (f16)a.y; hv[2] = (f16)a.z; hv[3] = (f16)a.w;
    hv[4] = (f16)b.x; hv[5] = (f16)b.y; hv[6] = (f16)b.z; hv[7] = (f16)b.w;
    ((half8*)dst)[off] = hv;
}

// ---------------------------------------------------------------------------
// V [4096][1024] f16 -> Vt [1024][4096] f16   (64x64 LDS tiles)
// ---------------------------------------------------------------------------
__global__ __launch_bounds__(256)
void transpose_v(const f16* __restrict__ V, f16* __restrict__ Vt)
{
    __shared__ f16 T[64][66];
    const int tid = threadIdx.x;
    const int t0 = blockIdx.x * 64, d0 = blockIdx.y * 64;
    const int r = tid >> 3, c = (tid & 7) * 8;
#pragma unroll
    for (int it = 0; it < 2; ++it) {
        int row = r + it * 32;
        half8 v = *(const half8*)(V + (size_t)(t0 + row) * DMODEL + d0 + c);
#pragma unroll
        for (int j = 0; j < 8; ++j) T[row][c + j] = v[j];
    }
    __syncthreads();
#pragma unroll
    for (int it = 0; it < 2; ++it) {
        int drow = r + it * 32;
        half8 v;
#pragma unroll
        for (int j = 0; j < 8; ++j) v[j] = T[c + j][drow];
        *(half8*)(Vt + (size_t)(d0 + drow) * TOKENS + t0 + c) = v;
    }
}

// ---------------------------------------------------------------------------
// f16 MFMA GEMM: C[M,N] = A[M,K] @ W[N,K]^T  (unchanged from round 5)
// ---------------------------------------------------------------------------
template<int MODE>
__global__ __launch_bounds__(256)
void gemm_f16(const f16* __restrict__ A, const f16* __restrict__ W0,
              const f16* __restrict__ W1, const f16* __restrict__ W2,
              const float* __restrict__ bias,
              f16* __restrict__ O0, f16* __restrict__ O1, f16* __restrict__ O2,
              float* __restrict__ Of, int K)
{
    __shared__ __align__(16) f16 As[128 * 64];
    __shared__ __align__(16) f16 Bs[128 * 64];
    const int tid = threadIdx.x, lane = tid & 63, wv = tid >> 6;
    const int g = lane >> 4, ln15 = lane & 15;
    const int bm = blockIdx.y, bn = blockIdx.x;
    const int rowInCall = lane >> 3, p = lane & 7;

    const f16* W = W0;
    f16* Oq = O0;
    int ncol0 = bn * 128;
    if (MODE == 0) {
        int which = bn >> 3;
        W  = which == 0 ? W0 : (which == 1 ? W1 : W2);
        Oq = which == 0 ? O0 : (which == 1 ? O1 : O2);
        ncol0 = (bn & 7) * 128;
    }

    f32x4 acc[4][4] = {};
    const size_t rowB = (size_t)K * 2;
    const int wm = (wv >> 1) * 64, wn = (wv & 1) * 64;

    for (int kt = 0; kt < K / 64; ++kt) {
        if (kt) __syncthreads();
        for (int c = wv * 4; c < wv * 4 + 4; ++c) {
            int r = c * 8 + rowInCall;
            int gc = p ^ (r & 7);
            const char* ga = (const char*)A + (size_t)(bm * 128 + r) * rowB + kt * 128 + gc * 16;
            gload16(ga, (char*)As + c * 1024);
            const char* gb = (const char*)W + (size_t)(ncol0 + r) * rowB + kt * 128 + gc * 16;
            gload16(gb, (char*)Bs + c * 1024);
        }
        __syncthreads();

#pragma unroll
        for (int ks = 0; ks < 2; ++ks) {
            half8 a[4], b[4];
#pragma unroll
            for (int mf = 0; mf < 4; ++mf)
                a[mf] = *(const half8*)lds_chunk(As, wm + mf * 16 + ln15, ks * 4 + g);
#pragma unroll
            for (int nf = 0; nf < 4; ++nf)
                b[nf] = *(const half8*)lds_chunk(Bs, wn + nf * 16 + ln15, ks * 4 + g);
#pragma unroll
            for (int mf = 0; mf < 4; ++mf)
#pragma unroll
                for (int nf = 0; nf < 4; ++nf)
                    acc[mf][nf] = __builtin_amdgcn_mfma_f32_16x16x32_f16(
                        a[mf], b[nf], acc[mf][nf], 0, 0, 0);
        }
    }

#pragma unroll
    for (int mf = 0; mf < 4; ++mf)
#pragma unroll
        for (int nf = 0; nf < 4; ++nf)
#pragma unroll
            for (int r = 0; r < 4; ++r) {
                int row = bm * 128 + wm + mf * 16 + g * 4 + r;
                int col = wn + nf * 16 + ln15;
                if (MODE == 0) {
                    Oq[(size_t)row * 1024 + ncol0 + col] = (f16)acc[mf][nf][r];
                } else {
                    int gc2 = bn * 128 + col;
                    Of[(size_t)row * 1024 + gc2] = acc[mf][nf][r] + bias[gc2];
                }
            }
}

// ---------------------------------------------------------------------------
// Flash attention v2.
//  - causal pairing: block bx does q-tiles bx and 63-bx  -> 65 iters/block,
//    perfectly balanced; grid (32, 16) = 512 blocks, 2/CU (80 KB LDS).
//  - double-buffered K/V: stage(kb+1) issued BEFORE compute(kb); single
//    __syncthreads per iter drains the prefetch (T3-lite 2-phase).
//  - row-sum via ones-column MFMA into Osum (drops the 16-shfl sum tree).
//  - setprio(1) around MFMA clusters; 0.125 scale folded into Q frags.
// ---------------------------------------------------------------------------
__global__ __launch_bounds__(256)
void attn_f16(const f16* __restrict__ Qf, const f16* __restrict__ Kf,
              const f16* __restrict__ Vt, f16* __restrict__ Ctx)
{
    __shared__ __align__(16) f16 Ks[2][64 * 64];
    __shared__ __align__(16) f16 Vs[2][64 * 64];
    __shared__ __align__(16) f16 Ps[4][16 * 64];
    const int tid = threadIdx.x, lane = tid & 63, wv = tid >> 6;
    const int g = lane >> 4, ln15 = lane & 15;
    const int h = blockIdx.y;
    const int rowInCall = lane >> 3, p = lane & 7;
    char* Pb = (char*)Ps[wv];

    half8 b_ones;
#pragma unroll
    for (int j = 0; j < 8; ++j) b_ones[j] = (f16)1.0f;

    for (int ph = 0; ph < 2; ++ph) {
        const int qb = ph ? (63 - blockIdx.x) : blockIdx.x;

        // Q fragments in registers, pre-scaled by 1/sqrt(64) (exact in f16)
        const int qrow = qb * 64 + wv * 16 + ln15;
        half8 qfr[2];
#pragma unroll
        for (int ks = 0; ks < 2; ++ks) {
            qfr[ks] = *(const half8*)(Qf + (size_t)qrow * DMODEL + h * HDIM + ks * 32 + g * 8);
#pragma unroll
            for (int j = 0; j < 8; ++j) qfr[ks][j] = qfr[ks][j] * (f16)0.125f;
        }

        f32x4 O[4] = {};
        f32x4 Osum = {};
        float m_r[4] = {-1e30f, -1e30f, -1e30f, -1e30f};
        const int qrow_g = qb * 64 + wv * 16 + g * 4;

        // stage K/Vt tile kb into LDS buffer bi (2 gload16 x2 arrays / wave)
        auto stage = [&](int kb, int bi) {
            for (int c = wv * 2; c < wv * 2 + 2; ++c) {
                int r = c * 8 + rowInCall;
                int gc = p ^ (r & 7);
                const char* gk = (const char*)Kf + (size_t)(kb * 64 + r) * (DMODEL * 2)
                                 + h * 128 + gc * 16;
                gload16(gk, (char*)&Ks[bi][0] + c * 1024);
                const char* gv = (const char*)Vt + (size_t)(h * 64 + r) * (TOKENS * 2)
                                 + kb * 128 + gc * 16;
                gload16(gv, (char*)&Vs[bi][0] + c * 1024);
            }
        };

        stage(0, 0);
        __syncthreads();          // drain prologue loads
        int cur = 0;

        for (int kb = 0; kb <= qb; ++kb) {
            if (kb < qb) stage(kb + 1, cur ^ 1);   // prefetch overlaps compute

            // S = Q K^T  (16 q x 64 t per wave), pre-scaled
            f32x4 s[4] = {};
            __builtin_amdgcn_s_setprio(1);
#pragma unroll
            for (int ks = 0; ks < 2; ++ks)
#pragma unroll
                for (int tf = 0; tf < 4; ++tf) {
                    half8 b = *(const half8*)lds_chunk(&Ks[cur][0], tf * 16 + ln15, ks * 4 + g);
                    s[tf] = __builtin_amdgcn_mfma_f32_16x16x32_f16(qfr[ks], b, s[tf], 0, 0, 0);
                }
            __builtin_amdgcn_s_setprio(0);

            // causal mask + per-row tile max
            const bool diag = (kb == qb);
            float tmax[4] = {-1e30f, -1e30f, -1e30f, -1e30f};
#pragma unroll
            for (int tf = 0; tf < 4; ++tf) {
                int t = kb * 64 + tf * 16 + ln15;
#pragma unroll
                for (int r = 0; r < 4; ++r) {
                    float v = s[tf][r];
                    if (diag && t > qrow_g + r) v = -1e30f;
                    s[tf][r] = v;
                    tmax[r] = fmaxf(tmax[r], v);
                }
            }
#pragma unroll
            for (int r = 0; r < 4; ++r)
#pragma unroll
                for (int mm = 1; mm < 16; mm <<= 1)
                    tmax[r] = fmaxf(tmax[r], __shfl_xor(tmax[r], mm, 64));

            float corr[4];
#pragma unroll
            for (int r = 0; r < 4; ++r) {
                float mnew = fmaxf(m_r[r], tmax[r]);
                corr[r] = __expf(m_r[r] - mnew);
                m_r[r] = mnew;
            }

            // P = exp(S - m) -> f16 -> wave-private LDS (swizzled)
#pragma unroll
            for (int tf = 0; tf < 4; ++tf)
#pragma unroll
                for (int r = 0; r < 4; ++r) {
                    float e = __expf(s[tf][r] - m_r[r]);
                    int row = g * 4 + r;
                    int t = tf * 16 + ln15;
                    int pc = (t >> 3) ^ (row & 7);
                    *(f16*)(Pb + row * 128 + pc * 16 + (t & 7) * 2) = (f16)e;
                }

            // rescale accumulators
#pragma unroll
            for (int df = 0; df < 4; ++df)
#pragma unroll
                for (int r = 0; r < 4; ++r)
                    O[df][r] *= corr[r];
#pragma unroll
            for (int r = 0; r < 4; ++r) Osum[r] *= corr[r];

            // P writes -> P reads (same wave); rule #18 fence
            asm volatile("s_waitcnt lgkmcnt(0)" ::: "memory");
            __builtin_amdgcn_sched_barrier(0);

            __builtin_amdgcn_s_setprio(1);
#pragma unroll
            for (int ks = 0; ks < 2; ++ks) {
                half8 pa = *(const half8*)lds_chunk(Pb, ln15, ks * 4 + g);
                Osum = __builtin_amdgcn_mfma_f32_16x16x32_f16(pa, b_ones, Osum, 0, 0, 0);
#pragma unroll
                for (int df = 0; df < 4; ++df) {
                    half8 b = *(const half8*)lds_chunk(&Vs[cur][0], df * 16 + ln15, ks * 4 + g);
                    O[df] = __builtin_amdgcn_mfma_f32_16x16x32_f16(pa, b, O[df], 0, 0, 0);
                }
            }
            __builtin_amdgcn_s_setprio(0);

            __syncthreads();      // drains prefetch (vmcnt) + syncs buffers
            cur ^= 1;
        }

        // epilogue: normalize by Osum (flash ones-column row sums)
#pragma unroll
        for (int df = 0; df < 4; ++df)
#pragma unroll
            for (int r = 0; r < 4; ++r) {
                int row = qrow_g + r;
                int col = h * HDIM + df * 16 + ln15;
                Ctx[(size_t)row * DMODEL + col] = (f16)(O[df][r] / Osum[r]);
            }
        // no barrier needed: last iter's __syncthreads precedes any phase-2
        // restaging, and the epilogue touches no LDS.
    }
}

// ---------------------------------------------------------------------------
extern "C" void kernel_launch(void* const* d_in, const int* in_sizes, int n_in,
                              void* d_out, int out_size, void* d_ws, size_t ws_size,
                              hipStream_t stream)
{
    const float* x  = (const float*)d_in[0];
    const float* Wq = (const float*)d_in[1];
    const float* Wk = (const float*)d_in[2];
    const float* Wv = (const float*)d_in[3];
    const float* Wo = (const float*)d_in[4];
    const float* bo = (const float*)d_in[5];
    float* out = (float*)d_out;

    const size_t XN = (size_t)TOKENS * DMODEL;   // 4M
    const size_t WN = (size_t)DMODEL * DMODEL;   // 1M
    f16* xh  = (f16*)d_ws;
    f16* Wqh = xh  + XN;
    f16* Wkh = Wqh + WN;
    f16* Wvh = Wkh + WN;
    f16* Woh = Wvh + WN;
    f16* Q   = Woh + WN;
    f16* Kb  = Q   + XN;
    f16* Vb  = Kb  + XN;
    f16* Vtb = Vb  + XN;
    f16* Ctx = Vtb + XN;                          // total 28M f16 = 56 MB

    cvt_all<<<4096, 256, 0, stream>>>(x, Wq, Wk, Wv, Wo, xh, Wqh, Wkh, Wvh, Woh);

    gemm_f16<0><<<dim3(24, 32), 256, 0, stream>>>(xh, Wqh, Wkh, Wvh, nullptr,
                                                  Q, Kb, Vb, nullptr, DMODEL);
    transpose_v<<<dim3(TOKENS / 64, DMODEL / 64), 256, 0, stream>>>(Vb, Vtb);
    attn_f16<<<dim3(32, NHEADS), 256, 0, stream>>>(Q, Kb, Vtb, Ctx);
    gemm_f16<1><<<dim3(8, 32), 256, 0, stream>>>(Ctx, Woh, nullptr, nullptr, bo,
                                                 nullptr, nullptr, nullptr, out, DMODEL);
}

// Round 10
// 226.811 us; speedup vs baseline: 8.4683x; 1.0879x over previous
//
#include <hip/hip_runtime.h>
#include <cmath>

#define TOKENS 4096
#define DMODEL 1024
#define NHEADS 16
#define HDIM 64

typedef _Float16 f16;
typedef _Float16 half8 __attribute__((ext_vector_type(8)));
typedef __fp16 fp16x2 __attribute__((ext_vector_type(2)));   // cvt_pkrtz return type
typedef float f32x4 __attribute__((ext_vector_type(4)));

#define EXP2F(x) __builtin_amdgcn_exp2f(x)
#define SCALE_Q 0.18033688011112042f   /* 0.125 * log2(e): exp2-domain scores */

// ---------------------------------------------------------------------------
// Swizzled LDS tiles: rows of 128 bytes = 8 chunks of 16 B.
// Logical chunk g of row r lives at physical chunk g ^ (r & 7).
// Staged via global_load_lds with PRE-SWIZZLED per-lane global source.
// ---------------------------------------------------------------------------
__device__ __forceinline__ void* lds_chunk(void* base, int row, int chunk) {
    int p = chunk ^ (row & 7);
    return (char*)base + row * 128 + p * 16;
}

__device__ __forceinline__ void gload16(const void* g, void* lds) {
    __builtin_amdgcn_global_load_lds(
        (const __attribute__((address_space(1))) unsigned int*)g,
        (__attribute__((address_space(3))) unsigned int*)lds, 16, 0, 0);
}

// ---------------------------------------------------------------------------
// Fused f32->f16 convert for x, Wq, Wk, Wv, Wo (one launch).
// ---------------------------------------------------------------------------
__global__ __launch_bounds__(256)
void cvt_all(const float* __restrict__ x,  const float* __restrict__ Wq,
             const float* __restrict__ Wk, const float* __restrict__ Wv,
             const float* __restrict__ Wo,
             f16* xh, f16* Wqh, f16* Wkh, f16* Wvh, f16* Woh)
{
    int i = blockIdx.x * 256 + threadIdx.x;
    const float* src; f16* dst; int off;
    if      (i < 524288) { src = x;  dst = xh;  off = i; }
    else if (i < 655360) { src = Wq; dst = Wqh; off = i - 524288; }
    else if (i < 786432) { src = Wk; dst = Wkh; off = i - 655360; }
    else if (i < 917504) { src = Wv; dst = Wvh; off = i - 786432; }
    else                 { src = Wo; dst = Woh; off = i - 917504; }
    float4 a = ((const float4*)src)[off * 2];
    float4 b = ((const float4*)src)[off * 2 + 1];
    half8 hv;
    hv[0] = (f16)a.x; hv[1] = (f16)a.y; hv[2] = (f16)a.z; hv[3] = (f16)a.w;
    hv[4] = (f16)b.x; hv[5] = (f16)b.y; hv[6] = (f16)b.z; hv[7] = (f16)b.w;
    ((half8*)dst)[off] = hv;
}

// ---------------------------------------------------------------------------
// V [4096][1024] f16 -> Vt [1024][4096] f16   (64x64 LDS tiles)
// ---------------------------------------------------------------------------
__global__ __launch_bounds__(256)
void transpose_v(const f16* __restrict__ V, f16* __restrict__ Vt)
{
    __shared__ f16 T[64][66];
    const int tid = threadIdx.x;
    const int t0 = blockIdx.x * 64, d0 = blockIdx.y * 64;
    const int r = tid >> 3, c = (tid & 7) * 8;
#pragma unroll
    for (int it = 0; it < 2; ++it) {
        int row = r + it * 32;
        half8 v = *(const half8*)(V + (size_t)(t0 + row) * DMODEL + d0 + c);
#pragma unroll
        for (int j = 0; j < 8; ++j) T[row][c + j] = v[j];
    }
    __syncthreads();
#pragma unroll
    for (int it = 0; it < 2; ++it) {
        int drow = r + it * 32;
        half8 v;
#pragma unroll
        for (int j = 0; j < 8; ++j) v[j] = T[c + j][drow];
        *(half8*)(Vt + (size_t)(d0 + drow) * TOKENS + t0 + c) = v;
    }
}

// ---------------------------------------------------------------------------
// f16 MFMA GEMM: C[M,N] = A[M,K] @ W[N,K]^T
// MODE 0: fused QKV; Q-third accumulators scaled by 0.125*log2(e) in f32.
// MODE 1: f32 out + bias.
// ---------------------------------------------------------------------------
template<int MODE>
__global__ __launch_bounds__(256)
void gemm_f16(const f16* __restrict__ A, const f16* __restrict__ W0,
              const f16* __restrict__ W1, const f16* __restrict__ W2,
              const float* __restrict__ bias,
              f16* __restrict__ O0, f16* __restrict__ O1, f16* __restrict__ O2,
              float* __restrict__ Of, int K)
{
    __shared__ __align__(16) f16 As[128 * 64];
    __shared__ __align__(16) f16 Bs[128 * 64];
    const int tid = threadIdx.x, lane = tid & 63, wv = tid >> 6;
    const int g = lane >> 4, ln15 = lane & 15;
    const int bm = blockIdx.y, bn = blockIdx.x;
    const int rowInCall = lane >> 3, p = lane & 7;

    const f16* W = W0;
    f16* Oq = O0;
    int ncol0 = bn * 128;
    int which = 0;
    if (MODE == 0) {
        which = bn >> 3;
        W  = which == 0 ? W0 : (which == 1 ? W1 : W2);
        Oq = which == 0 ? O0 : (which == 1 ? O1 : O2);
        ncol0 = (bn & 7) * 128;
    }

    f32x4 acc[4][4] = {};
    const size_t rowB = (size_t)K * 2;
    const int wm = (wv >> 1) * 64, wn = (wv & 1) * 64;

    for (int kt = 0; kt < K / 64; ++kt) {
        if (kt) __syncthreads();
        for (int c = wv * 4; c < wv * 4 + 4; ++c) {
            int r = c * 8 + rowInCall;
            int gc = p ^ (r & 7);
            const char* ga = (const char*)A + (size_t)(bm * 128 + r) * rowB + kt * 128 + gc * 16;
            gload16(ga, (char*)As + c * 1024);
            const char* gb = (const char*)W + (size_t)(ncol0 + r) * rowB + kt * 128 + gc * 16;
            gload16(gb, (char*)Bs + c * 1024);
        }
        __syncthreads();

#pragma unroll
        for (int ks = 0; ks < 2; ++ks) {
            half8 a[4], b[4];
#pragma unroll
            for (int mf = 0; mf < 4; ++mf)
                a[mf] = *(const half8*)lds_chunk(As, wm + mf * 16 + ln15, ks * 4 + g);
#pragma unroll
            for (int nf = 0; nf < 4; ++nf)
                b[nf] = *(const half8*)lds_chunk(Bs, wn + nf * 16 + ln15, ks * 4 + g);
#pragma unroll
            for (int mf = 0; mf < 4; ++mf)
#pragma unroll
                for (int nf = 0; nf < 4; ++nf)
                    acc[mf][nf] = __builtin_amdgcn_mfma_f32_16x16x32_f16(
                        a[mf], b[nf], acc[mf][nf], 0, 0, 0);
        }
    }

#pragma unroll
    for (int mf = 0; mf < 4; ++mf)
#pragma unroll
        for (int nf = 0; nf < 4; ++nf)
#pragma unroll
            for (int r = 0; r < 4; ++r) {
                int row = bm * 128 + wm + mf * 16 + g * 4 + r;
                int col = wn + nf * 16 + ln15;
                float val = acc[mf][nf][r];
                if (MODE == 0) {
                    if (which == 0) val *= SCALE_Q;   // exp2-domain Q
                    Oq[(size_t)row * 1024 + ncol0 + col] = (f16)val;
                } else {
                    int gc2 = bn * 128 + col;
                    Of[(size_t)row * 1024 + gc2] = val + bias[gc2];
                }
            }
}

// ---------------------------------------------------------------------------
// Flash attention v3b (swapped-QK^T, exp2 domain, defer-max, balanced grid).
//  - grid 1024: xcd = id&7 owns heads {2xcd, 2xcd+1} (K/V 2 MB fits per-XCD
//    L2). slot = id>>3: c = slot&31, j = slot>>5; h = 2xcd + (j>>1);
//    qb = (j&1) ? 63-c : c.  Under round-robin dispatch each CU's 4 resident
//    blocks have qb {c, 63-c, c, 63-c} -> constant 130 t-tiles per CU
//    (causal pairing at the CU level, 4 blocks/CU with 40 KB LDS).
//  - S^T = mfma(K, Q): lane holds one q-row; in-lane max + 2 shfl;
//    P packed via cvt_pkrtz -> 4x ds_write_b64 (swizzled, wave-private).
//  - defer-max: skip corr/rescale unless __all(tmax <= m+8) fails.
//  - double-buffered K/V staging; ones-column MFMA row sums.
// ---------------------------------------------------------------------------
__global__ __launch_bounds__(256)
void attn_f16(const f16* __restrict__ Qf, const f16* __restrict__ Kf,
              const f16* __restrict__ Vt, f16* __restrict__ Ctx)
{
    __shared__ __align__(16) f16 Ks[2][64 * 64];
    __shared__ __align__(16) f16 Vs[2][64 * 64];
    __shared__ __align__(16) f16 Ps[4][16 * 64];
    const int tid = threadIdx.x, lane = tid & 63, wv = tid >> 6;
    const int g = lane >> 4, ln15 = lane & 15;
    const int rowInCall = lane >> 3, p = lane & 7;

    const int id = blockIdx.x;
    const int xcd = id & 7, slot = id >> 3;
    const int c_ = slot & 31, j_ = slot >> 5;
    const int h  = xcd * 2 + (j_ >> 1);
    const int qb = (j_ & 1) ? (63 - c_) : c_;

    char* Pb = (char*)Ps[wv];

    half8 b_ones;
#pragma unroll
    for (int j = 0; j < 8; ++j) b_ones[j] = (f16)1.0f;

    // Q fragments (B-operand of S^T): lane ln15 = q, k-slice by g
    const int qrow = qb * 64 + wv * 16 + ln15;
    half8 qfr[2];
#pragma unroll
    for (int ks = 0; ks < 2; ++ks)
        qfr[ks] = *(const half8*)(Qf + (size_t)qrow * DMODEL + h * HDIM + ks * 32 + g * 8);

    f32x4 O[4] = {};
    f32x4 Osum = {};
    float m_q = -1e30f;                      // per-lane: this lane's q-row max
    const int qrow_g = qb * 64 + wv * 16 + g * 4;   // C-layout row base

    auto stage = [&](int kb, int bi) {
        for (int c = wv * 2; c < wv * 2 + 2; ++c) {
            int r = c * 8 + rowInCall;
            int gc = p ^ (r & 7);
            const char* gk = (const char*)Kf + (size_t)(kb * 64 + r) * (DMODEL * 2)
                             + h * 128 + gc * 16;
            gload16(gk, (char*)&Ks[bi][0] + c * 1024);
            const char* gv = (const char*)Vt + (size_t)(h * 64 + r) * (TOKENS * 2)
                             + kb * 128 + gc * 16;
            gload16(gv, (char*)&Vs[bi][0] + c * 1024);
        }
    };

    stage(0, 0);
    __syncthreads();
    int cur = 0;

    for (int kb = 0; kb <= qb; ++kb) {
        if (kb < qb) stage(kb + 1, cur ^ 1);   // prefetch overlaps compute

        // S^T = K Q^T : rows t = tf*16 + g*4 + r, col q = ln15 (per lane)
        f32x4 s[4] = {};
        __builtin_amdgcn_s_setprio(1);
#pragma unroll
        for (int ks = 0; ks < 2; ++ks)
#pragma unroll
            for (int tf = 0; tf < 4; ++tf) {
                half8 a = *(const half8*)lds_chunk(&Ks[cur][0], tf * 16 + ln15, ks * 4 + g);
                s[tf] = __builtin_amdgcn_mfma_f32_16x16x32_f16(a, qfr[ks], s[tf], 0, 0, 0);
            }
        __builtin_amdgcn_s_setprio(0);

        if (kb == qb) {                        // diagonal tile: mask t > q
#pragma unroll
            for (int tf = 0; tf < 4; ++tf)
#pragma unroll
                for (int r = 0; r < 4; ++r)
                    if (kb * 64 + tf * 16 + g * 4 + r > qrow) s[tf][r] = -1e30f;
        }

        // row max: in-lane over 16 values, then across the 4 g-copies
        float tmax = s[0][0];
#pragma unroll
        for (int tf = 0; tf < 4; ++tf)
#pragma unroll
            for (int r = 0; r < 4; ++r) tmax = fmaxf(tmax, s[tf][r]);
        tmax = fmaxf(tmax, __shfl_xor(tmax, 16, 64));
        tmax = fmaxf(tmax, __shfl_xor(tmax, 32, 64));

        // defer-max: rescale only when some row's max grew past m+8
        if (!__all(tmax <= m_q + 8.0f)) {
            float mnew = fmaxf(m_q, tmax);
            float corr = EXP2F(m_q - mnew);
            m_q = mnew;
            float cr[4];
#pragma unroll
            for (int r = 0; r < 4; ++r) cr[r] = __shfl(corr, g * 4 + r, 64);
#pragma unroll
            for (int df = 0; df < 4; ++df)
#pragma unroll
                for (int r = 0; r < 4; ++r) O[df][r] *= cr[r];
#pragma unroll
            for (int r = 0; r < 4; ++r) Osum[r] *= cr[r];
        }

        // P = exp2(S - m): 4 consecutive t per frag -> pack -> ds_write_b64
#pragma unroll
        for (int tf = 0; tf < 4; ++tf) {
            float e0 = EXP2F(s[tf][0] - m_q);
            float e1 = EXP2F(s[tf][1] - m_q);
            float e2 = EXP2F(s[tf][2] - m_q);
            float e3 = EXP2F(s[tf][3] - m_q);
            fp16x2 lo = __builtin_amdgcn_cvt_pkrtz(e0, e1);
            fp16x2 hi = __builtin_amdgcn_cvt_pkrtz(e2, e3);
            int pc = ((tf << 1) | (g >> 1)) ^ (ln15 & 7);
            union { fp16x2 h2[2]; double d; } u;
            u.h2[0] = lo; u.h2[1] = hi;
            *(double*)(Pb + ln15 * 128 + pc * 16 + (g & 1) * 8) = u.d;
        }

        // P writes -> P reads (same wave); rule #18 fence
        asm volatile("s_waitcnt lgkmcnt(0)" ::: "memory");
        __builtin_amdgcn_sched_barrier(0);

        __builtin_amdgcn_s_setprio(1);
#pragma unroll
        for (int ks = 0; ks < 2; ++ks) {
            half8 pa = *(const half8*)lds_chunk(Pb, ln15, ks * 4 + g);
            Osum = __builtin_amdgcn_mfma_f32_16x16x32_f16(pa, b_ones, Osum, 0, 0, 0);
#pragma unroll
            for (int df = 0; df < 4; ++df) {
                half8 b = *(const half8*)lds_chunk(&Vs[cur][0], df * 16 + ln15, ks * 4 + g);
                O[df] = __builtin_amdgcn_mfma_f32_16x16x32_f16(pa, b, O[df], 0, 0, 0);
            }
        }
        __builtin_amdgcn_s_setprio(0);

        __syncthreads();      // drains prefetch (vmcnt) + protects both buffers
        cur ^= 1;
    }

    // epilogue: O and Osum share C layout (row q = g*4+r, col d = df*16+ln15)
#pragma unroll
    for (int df = 0; df < 4; ++df)
#pragma unroll
        for (int r = 0; r < 4; ++r) {
            int row = qrow_g + r;
            int col = h * HDIM + df * 16 + ln15;
            Ctx[(size_t)row * DMODEL + col] = (f16)(O[df][r] / Osum[r]);
        }
}

// ---------------------------------------------------------------------------
extern "C" void kernel_launch(void* const* d_in, const int* in_sizes, int n_in,
                              void* d_out, int out_size, void* d_ws, size_t ws_size,
                              hipStream_t stream)
{
    const float* x  = (const float*)d_in[0];
    const float* Wq = (const float*)d_in[1];
    const float* Wk = (const float*)d_in[2];
    const float* Wv = (const float*)d_in[3];
    const float* Wo = (const float*)d_in[4];
    const float* bo = (const float*)d_in[5];
    float* out = (float*)d_out;

    const size_t XN = (size_t)TOKENS * DMODEL;   // 4M
    const size_t WN = (size_t)DMODEL * DMODEL;   // 1M
    f16* xh  = (f16*)d_ws;
    f16* Wqh = xh  + XN;
    f16* Wkh = Wqh + WN;
    f16* Wvh = Wkh + WN;
    f16* Woh = Wvh + WN;
    f16* Q   = Woh + WN;
    f16* Kb  = Q   + XN;
    f16* Vb  = Kb  + XN;
    f16* Vtb = Vb  + XN;
    f16* Ctx = Vtb + XN;                          // total 28M f16 = 56 MB

    cvt_all<<<4096, 256, 0, stream>>>(x, Wq, Wk, Wv, Wo, xh, Wqh, Wkh, Wvh, Woh);

    gemm_f16<0><<<dim3(24, 32), 256, 0, stream>>>(xh, Wqh, Wkh, Wvh, nullptr,
                                                  Q, Kb, Vb, nullptr, DMODEL);
    transpose_v<<<dim3(TOKENS / 64, DMODEL / 64), 256, 0, stream>>>(Vb, Vtb);
    attn_f16<<<1024, 256, 0, stream>>>(Q, Kb, Vtb, Ctx);
    gemm_f16<1><<<dim3(8, 32), 256, 0, stream>>>(Ctx, Woh, nullptr, nullptr, bo,
                                                 nullptr, nullptr, nullptr, out, DMODEL);
}

// Round 12
// 225.965 us; speedup vs baseline: 8.5000x; 1.0037x over previous
//
#include <hip/hip_runtime.h>
#include <cmath>

#define TOKENS 4096
#define DMODEL 1024
#define NHEADS 16
#define HDIM 64

typedef _Float16 f16;
typedef _Float16 half8 __attribute__((ext_vector_type(8)));
typedef __fp16 fp16x2 __attribute__((ext_vector_type(2)));   // cvt_pkrtz return type
typedef float f32x4 __attribute__((ext_vector_type(4)));

#define EXP2F(x) __builtin_amdgcn_exp2f(x)
#define SCALE_Q 0.18033688011112042f   /* 0.125 * log2(e): exp2-domain scores */

// ---------------------------------------------------------------------------
// Swizzled LDS tiles: rows of 128 bytes = 8 chunks of 16 B.
// Logical chunk g of row r lives at physical chunk g ^ (r & 7).
// Staged via global_load_lds with PRE-SWIZZLED per-lane global source.
// ---------------------------------------------------------------------------
__device__ __forceinline__ void* lds_chunk(void* base, int row, int chunk) {
    int p = chunk ^ (row & 7);
    return (char*)base + row * 128 + p * 16;
}

__device__ __forceinline__ void gload16(const void* g, void* lds) {
    __builtin_amdgcn_global_load_lds(
        (const __attribute__((address_space(1))) unsigned int*)g,
        (__attribute__((address_space(3))) unsigned int*)lds, 16, 0, 0);
}

// ---------------------------------------------------------------------------
// Fused f32->f16 convert for x, Wq, Wk, Wv, Wo (one launch).
// ---------------------------------------------------------------------------
__global__ __launch_bounds__(256)
void cvt_all(const float* __restrict__ x,  const float* __restrict__ Wq,
             const float* __restrict__ Wk, const float* __restrict__ Wv,
             const float* __restrict__ Wo,
             f16* xh, f16* Wqh, f16* Wkh, f16* Wvh, f16* Woh)
{
    int i = blockIdx.x * 256 + threadIdx.x;
    const float* src; f16* dst; int off;
    if      (i < 524288) { src = x;  dst = xh;  off = i; }
    else if (i < 655360) { src = Wq; dst = Wqh; off = i - 524288; }
    else if (i < 786432) { src = Wk; dst = Wkh; off = i - 655360; }
    else if (i < 917504) { src = Wv; dst = Wvh; off = i - 786432; }
    else                 { src = Wo; dst = Woh; off = i - 917504; }
    float4 a = ((const float4*)src)[off * 2];
    float4 b = ((const float4*)src)[off * 2 + 1];
    half8 hv;
    hv[0] = (f16)a.x; hv[1] = (f16)a.y; hv[2] = (f16)a.z; hv[3] = (f16)a.w;
    hv[4] = (f16)b.x; hv[5] = (f16)b.y; hv[6] = (f16)b.z; hv[7] = (f16)b.w;
    ((half8*)dst)[off] = hv;
}

// ---------------------------------------------------------------------------
// V [4096][1024] f16 -> Vt [1024][4096] f16   (64x64 LDS tiles)
// ---------------------------------------------------------------------------
__global__ __launch_bounds__(256)
void transpose_v(const f16* __restrict__ V, f16* __restrict__ Vt)
{
    __shared__ f16 T[64][66];
    const int tid = threadIdx.x;
    const int t0 = blockIdx.x * 64, d0 = blockIdx.y * 64;
    const int r = tid >> 3, c = (tid & 7) * 8;
#pragma unroll
    for (int it = 0; it < 2; ++it) {
        int row = r + it * 32;
        half8 v = *(const half8*)(V + (size_t)(t0 + row) * DMODEL + d0 + c);
#pragma unroll
        for (int j = 0; j < 8; ++j) T[row][c + j] = v[j];
    }
    __syncthreads();
#pragma unroll
    for (int it = 0; it < 2; ++it) {
        int drow = r + it * 32;
        half8 v;
#pragma unroll
        for (int j = 0; j < 8; ++j) v[j] = T[c + j][drow];
        *(half8*)(Vt + (size_t)(d0 + drow) * TOKENS + t0 + c) = v;
    }
}

// ---------------------------------------------------------------------------
// f16 MFMA GEMM: C[M,N] = A[M,K] @ W[N,K]^T
// MODE 0: fused QKV; Q-third accumulators scaled by 0.125*log2(e) in f32.
// MODE 1: f32 out + bias.
// ---------------------------------------------------------------------------
template<int MODE>
__global__ __launch_bounds__(256)
void gemm_f16(const f16* __restrict__ A, const f16* __restrict__ W0,
              const f16* __restrict__ W1, const f16* __restrict__ W2,
              const float* __restrict__ bias,
              f16* __restrict__ O0, f16* __restrict__ O1, f16* __restrict__ O2,
              float* __restrict__ Of, int K)
{
    __shared__ __align__(16) f16 As[128 * 64];
    __shared__ __align__(16) f16 Bs[128 * 64];
    const int tid = threadIdx.x, lane = tid & 63, wv = tid >> 6;
    const int g = lane >> 4, ln15 = lane & 15;
    const int bm = blockIdx.y, bn = blockIdx.x;
    const int rowInCall = lane >> 3, p = lane & 7;

    const f16* W = W0;
    f16* Oq = O0;
    int ncol0 = bn * 128;
    int which = 0;
    if (MODE == 0) {
        which = bn >> 3;
        W  = which == 0 ? W0 : (which == 1 ? W1 : W2);
        Oq = which == 0 ? O0 : (which == 1 ? O1 : O2);
        ncol0 = (bn & 7) * 128;
    }

    f32x4 acc[4][4] = {};
    const size_t rowB = (size_t)K * 2;
    const int wm = (wv >> 1) * 64, wn = (wv & 1) * 64;

    for (int kt = 0; kt < K / 64; ++kt) {
        if (kt) __syncthreads();
        for (int c = wv * 4; c < wv * 4 + 4; ++c) {
            int r = c * 8 + rowInCall;
            int gc = p ^ (r & 7);
            const char* ga = (const char*)A + (size_t)(bm * 128 + r) * rowB + kt * 128 + gc * 16;
            gload16(ga, (char*)As + c * 1024);
            const char* gb = (const char*)W + (size_t)(ncol0 + r) * rowB + kt * 128 + gc * 16;
            gload16(gb, (char*)Bs + c * 1024);
        }
        __syncthreads();

#pragma unroll
        for (int ks = 0; ks < 2; ++ks) {
            half8 a[4], b[4];
#pragma unroll
            for (int mf = 0; mf < 4; ++mf)
                a[mf] = *(const half8*)lds_chunk(As, wm + mf * 16 + ln15, ks * 4 + g);
#pragma unroll
            for (int nf = 0; nf < 4; ++nf)
                b[nf] = *(const half8*)lds_chunk(Bs, wn + nf * 16 + ln15, ks * 4 + g);
#pragma unroll
            for (int mf = 0; mf < 4; ++mf)
#pragma unroll
                for (int nf = 0; nf < 4; ++nf)
                    acc[mf][nf] = __builtin_amdgcn_mfma_f32_16x16x32_f16(
                        a[mf], b[nf], acc[mf][nf], 0, 0, 0);
        }
    }

#pragma unroll
    for (int mf = 0; mf < 4; ++mf)
#pragma unroll
        for (int nf = 0; nf < 4; ++nf)
#pragma unroll
            for (int r = 0; r < 4; ++r) {
                int row = bm * 128 + wm + mf * 16 + g * 4 + r;
                int col = wn + nf * 16 + ln15;
                float val = acc[mf][nf][r];
                if (MODE == 0) {
                    if (which == 0) val *= SCALE_Q;   // exp2-domain Q
                    Oq[(size_t)row * 1024 + ncol0 + col] = (f16)val;
                } else {
                    int gc2 = bn * 128 + col;
                    Of[(size_t)row * 1024 + gc2] = val + bias[gc2];
                }
            }
}

// ---------------------------------------------------------------------------
// Flash attention v4: v3b + loop-invariant address precompute.
// All LDS read offsets share rb[ks] = ln15*128 + ((ks*4+g)^(ln15&7))*16
// (row ≡ ln15 mod 8 for K/V/P reads); tf/df become ds offset: immediates.
// P-write addrs: 4 precomputed pointers via (x^y)<<4 = (x<<4)^(y<<4).
// Staging: 4 advancing per-lane pointers (+131072 B for K rows, +128 B for
// Vt cols per tile). Everything else identical to v3b (round 10, measured).
// ---------------------------------------------------------------------------
__global__ __launch_bounds__(256)
void attn_f16(const f16* __restrict__ Qf, const f16* __restrict__ Kf,
              const f16* __restrict__ Vt, f16* __restrict__ Ctx)
{
    __shared__ __align__(16) f16 Ks[2][64 * 64];
    __shared__ __align__(16) f16 Vs[2][64 * 64];
    __shared__ __align__(16) f16 Ps[4][16 * 64];
    const int tid = threadIdx.x, lane = tid & 63, wv = tid >> 6;
    const int g = lane >> 4, ln15 = lane & 15;
    const int rowInCall = lane >> 3, p = lane & 7;

    const int id = blockIdx.x;
    const int xcd = id & 7, slot = id >> 3;
    const int c_ = slot & 31, j_ = slot >> 5;
    const int h  = xcd * 2 + (j_ >> 1);
    const int qb = (j_ & 1) ? (63 - c_) : c_;

    char* Pb = (char*)Ps[wv];

    half8 b_ones;
#pragma unroll
    for (int j = 0; j < 8; ++j) b_ones[j] = (f16)1.0f;

    // ---- loop-invariant addressing ----
    int rb[2];
#pragma unroll
    for (int ks = 0; ks < 2; ++ks)
        rb[ks] = ln15 * 128 + (((ks * 4 + g) ^ (ln15 & 7)) << 4);
    // P read addrs (wave-private buffer, fixed)
    const char* prd[2] = { Pb + rb[0], Pb + rb[1] };
    // P write addrs: base ^ (tf<<5), precomputed per tf
    const int pwb = ln15 * 128 + ((((g >> 1)) ^ (ln15 & 7)) << 4) + (g & 1) * 8;
    char* pwr[4];
#pragma unroll
    for (int tf = 0; tf < 4; ++tf) pwr[tf] = Pb + (pwb ^ (tf << 5));

    // staging pointers (advance per tile): 2 calls/wave for K and for Vt
    const int sr0 = (wv * 2) * 8 + rowInCall;        // rows 0..63
    const int sr1 = (wv * 2 + 1) * 8 + rowInCall;
    const char* gkp0 = (const char*)Kf + (size_t)sr0 * (DMODEL * 2) + h * 128 + ((p ^ (sr0 & 7)) << 4);
    const char* gkp1 = (const char*)Kf + (size_t)sr1 * (DMODEL * 2) + h * 128 + ((p ^ (sr1 & 7)) << 4);
    const char* gvp0 = (const char*)Vt + (size_t)(h * 64 + sr0) * (TOKENS * 2) + ((p ^ (sr0 & 7)) << 4);
    const char* gvp1 = (const char*)Vt + (size_t)(h * 64 + sr1) * (TOKENS * 2) + ((p ^ (sr1 & 7)) << 4);
    char* dK0 = (char*)Ks + (wv * 2) * 1024;         // bi toggles +8192
    char* dV0 = (char*)Vs + (wv * 2) * 1024;

    // Q fragments (B-operand of S^T): lane ln15 = q, k-slice by g
    const int qrow = qb * 64 + wv * 16 + ln15;
    half8 qfr[2];
#pragma unroll
    for (int ks = 0; ks < 2; ++ks)
        qfr[ks] = *(const half8*)(Qf + (size_t)qrow * DMODEL + h * HDIM + ks * 32 + g * 8);

    f32x4 O[4] = {};
    f32x4 Osum = {};
    float m_q = -1e30f;
    const int qrow_g = qb * 64 + wv * 16 + g * 4;

    auto stage2 = [&](int bi) {
        const int bo = bi << 13;
        gload16(gkp0, dK0 + bo);
        gload16(gkp1, dK0 + bo + 1024);
        gload16(gvp0, dV0 + bo);
        gload16(gvp1, dV0 + bo + 1024);
        gkp0 += 64 * DMODEL * 2;  gkp1 += 64 * DMODEL * 2;   // next 64 K-rows
        gvp0 += 128;              gvp1 += 128;               // next 64 Vt-cols
    };

    stage2(0);             // stages kb=0; pointers now at kb=1
    __syncthreads();
    int cur = 0;

    for (int kb = 0; kb <= qb; ++kb) {
        if (kb < qb) stage2(cur ^ 1);   // prefetch kb+1 overlaps compute

        const char* kcur = (const char*)Ks + (cur << 13);
        const char* vcur = (const char*)Vs + (cur << 13);

        // S^T = K Q^T : rows t = tf*16 + g*4 + r, col q = ln15 (per lane)
        f32x4 s[4] = {};
        __builtin_amdgcn_s_setprio(1);
#pragma unroll
        for (int ks = 0; ks < 2; ++ks) {
            const char* ka = kcur + rb[ks];
#pragma unroll
            for (int tf = 0; tf < 4; ++tf) {
                half8 a = *(const half8*)(ka + tf * 2048);
                s[tf] = __builtin_amdgcn_mfma_f32_16x16x32_f16(a, qfr[ks], s[tf], 0, 0, 0);
            }
        }
        __builtin_amdgcn_s_setprio(0);

        if (kb == qb) {                        // diagonal tile: mask t > q
#pragma unroll
            for (int tf = 0; tf < 4; ++tf)
#pragma unroll
                for (int r = 0; r < 4; ++r)
                    if (kb * 64 + tf * 16 + g * 4 + r > qrow) s[tf][r] = -1e30f;
        }

        // row max: in-lane over 16 values, then across the 4 g-copies
        float tmax = s[0][0];
#pragma unroll
        for (int tf = 0; tf < 4; ++tf)
#pragma unroll
            for (int r = 0; r < 4; ++r) tmax = fmaxf(tmax, s[tf][r]);
        tmax = fmaxf(tmax, __shfl_xor(tmax, 16, 64));
        tmax = fmaxf(tmax, __shfl_xor(tmax, 32, 64));

        // defer-max: rescale only when some row's max grew past m+8
        if (!__all(tmax <= m_q + 8.0f)) {
            float mnew = fmaxf(m_q, tmax);
            float corr = EXP2F(m_q - mnew);
            m_q = mnew;
            float cr[4];
#pragma unroll
            for (int r = 0; r < 4; ++r) cr[r] = __shfl(corr, g * 4 + r, 64);
#pragma unroll
            for (int df = 0; df < 4; ++df)
#pragma unroll
                for (int r = 0; r < 4; ++r) O[df][r] *= cr[r];
#pragma unroll
            for (int r = 0; r < 4; ++r) Osum[r] *= cr[r];
        }

        // P = exp2(S - m): pack -> 4x ds_write_b64 at precomputed addrs
#pragma unroll
        for (int tf = 0; tf < 4; ++tf) {
            float e0 = EXP2F(s[tf][0] - m_q);
            float e1 = EXP2F(s[tf][1] - m_q);
            float e2 = EXP2F(s[tf][2] - m_q);
            float e3 = EXP2F(s[tf][3] - m_q);
            fp16x2 lo = __builtin_amdgcn_cvt_pkrtz(e0, e1);
            fp16x2 hi = __builtin_amdgcn_cvt_pkrtz(e2, e3);
            union { fp16x2 h2[2]; double d; } u;
            u.h2[0] = lo; u.h2[1] = hi;
            *(double*)pwr[tf] = u.d;
        }

        // P writes -> P reads (same wave); rule #18 fence
        asm volatile("s_waitcnt lgkmcnt(0)" ::: "memory");
        __builtin_amdgcn_sched_barrier(0);

        __builtin_amdgcn_s_setprio(1);
#pragma unroll
        for (int ks = 0; ks < 2; ++ks) {
            half8 pa = *(const half8*)prd[ks];
            Osum = __builtin_amdgcn_mfma_f32_16x16x32_f16(pa, b_ones, Osum, 0, 0, 0);
            const char* va = vcur + rb[ks];
#pragma unroll
            for (int df = 0; df < 4; ++df) {
                half8 b = *(const half8*)(va + df * 2048);
                O[df] = __builtin_amdgcn_mfma_f32_16x16x32_f16(pa, b, O[df], 0, 0, 0);
            }
        }
        __builtin_amdgcn_s_setprio(0);

        __syncthreads();      // drains prefetch (vmcnt) + protects both buffers
        cur ^= 1;
    }

    // epilogue: O and Osum share C layout (row q = g*4+r, col d = df*16+ln15)
#pragma unroll
    for (int df = 0; df < 4; ++df)
#pragma unroll
        for (int r = 0; r < 4; ++r) {
            int row = qrow_g + r;
            int col = h * HDIM + df * 16 + ln15;
            Ctx[(size_t)row * DMODEL + col] = (f16)(O[df][r] / Osum[r]);
        }
}

// ---------------------------------------------------------------------------
extern "C" void kernel_launch(void* const* d_in, const int* in_sizes, int n_in,
                              void* d_out, int out_size, void* d_ws, size_t ws_size,
                              hipStream_t stream)
{
    const float* x  = (const float*)d_in[0];
    const float* Wq = (const float*)d_in[1];
    const float* Wk = (const float*)d_in[2];
    const float* Wv = (const float*)d_in[3];
    const float* Wo = (const float*)d_in[4];
    const float* bo = (const float*)d_in[5];
    float* out = (float*)d_out;

    const size_t XN = (size_t)TOKENS * DMODEL;   // 4M
    const size_t WN = (size_t)DMODEL * DMODEL;   // 1M
    f16* xh  = (f16*)d_ws;
    f16* Wqh = xh  + XN;
    f16* Wkh = Wqh + WN;
    f16* Wvh = Wkh + WN;
    f16* Woh = Wvh + WN;
    f16* Q   = Woh + WN;
    f16* Kb  = Q   + XN;
    f16* Vb  = Kb  + XN;
    f16* Vtb = Vb  + XN;
    f16* Ctx = Vtb + XN;                          // total 28M f16 = 56 MB

    cvt_all<<<4096, 256, 0, stream>>>(x, Wq, Wk, Wv, Wo, xh, Wqh, Wkh, Wvh, Woh);

    gemm_f16<0><<<dim3(24, 32), 256, 0, stream>>>(xh, Wqh, Wkh, Wvh, nullptr,
                                                  Q, Kb, Vb, nullptr, DMODEL);
    transpose_v<<<dim3(TOKENS / 64, DMODEL / 64), 256, 0, stream>>>(Vb, Vtb);
    attn_f16<<<1024, 256, 0, stream>>>(Q, Kb, Vtb, Ctx);
    gemm_f16<1><<<dim3(8, 32), 256, 0, stream>>>(Ctx, Woh, nullptr, nullptr, bo,
                                                 nullptr, nullptr, nullptr, out, DMODEL);
}